// Round 3
// baseline (2004.951 us; speedup 1.0000x reference)
//
#include <hip/hip_runtime.h>
#include <hip/hip_bf16.h>

// ---------------- constants ----------------
constexpr int CB   = 2;     // batch
constexpr int CS   = 2048;  // seq
constexpr int CH   = 2048;  // hidden
constexpr int CNH  = 16;    // heads
constexpr int CHD  = 128;   // head dim
constexpr int CE   = 8;     // experts
constexpr int CI   = 2048;  // ffn inner
constexpr int CT   = CB * CS;      // 4096 tokens
constexpr int CQKV = 3 * CH;       // 6144

typedef __attribute__((ext_vector_type(8))) short short8;
typedef __attribute__((ext_vector_type(4))) float float4v;

__device__ __forceinline__ float bf2f(unsigned short u) {
    union { unsigned int i; float f; } x; x.i = ((unsigned int)u) << 16; return x.f;
}
__device__ __forceinline__ unsigned short f2bf(float f) {
    union { float f; unsigned int i; } x; x.f = f;
    unsigned int r = x.i + 0x7fffu + ((x.i >> 16) & 1u);
    return (unsigned short)(r >> 16);
}
// split 8 consecutive floats into hi/lo bf16 (hi+lo carries ~17 mantissa bits)
__device__ __forceinline__ void split8(const float* s, short8& hi, short8& lo) {
    float4 a = *(const float4*)s, b = *(const float4*)(s + 4);
    float v[8] = {a.x, a.y, a.z, a.w, b.x, b.y, b.z, b.w};
    unsigned short* H = (unsigned short*)&hi;
    unsigned short* L = (unsigned short*)&lo;
    #pragma unroll
    for (int j = 0; j < 8; j++) {
        unsigned short h = f2bf(v[j]);
        H[j] = h;
        L[j] = f2bf(v[j] - bf2f(h));
    }
}

// ---------------- RMSNorm: fp32 in -> fp32 or bf16 out ----------------
template<int BF16OUT>
__global__ __launch_bounds__(256) void rmsnorm_k(const float* __restrict__ x,
                                                 const float* __restrict__ w,
                                                 void* __restrict__ outp) {
    const int row = blockIdx.x;
    const float* xr = x + (size_t)row * CH;
    const int base = threadIdx.x * 8;
    float4 v0 = *(const float4*)(xr + base);
    float4 v1 = *(const float4*)(xr + base + 4);
    float ss = v0.x*v0.x + v0.y*v0.y + v0.z*v0.z + v0.w*v0.w
             + v1.x*v1.x + v1.y*v1.y + v1.z*v1.z + v1.w*v1.w;
    #pragma unroll
    for (int o = 1; o < 64; o <<= 1) ss += __shfl_xor(ss, o);
    __shared__ float ps[4];
    if ((threadIdx.x & 63) == 0) ps[threadIdx.x >> 6] = ss;
    __syncthreads();
    const float scale = rsqrtf((ps[0] + ps[1] + ps[2] + ps[3]) / (float)CH + 1e-5f);
    float4 w0 = *(const float4*)(w + base);
    float4 w1 = *(const float4*)(w + base + 4);
    float r[8] = {v0.x * scale * w0.x, v0.y * scale * w0.y, v0.z * scale * w0.z, v0.w * scale * w0.w,
                  v1.x * scale * w1.x, v1.y * scale * w1.y, v1.z * scale * w1.z, v1.w * scale * w1.w};
    if (BF16OUT) {
        short8 ov;
        unsigned short* op = (unsigned short*)&ov;
        #pragma unroll
        for (int j = 0; j < 8; j++) op[j] = f2bf(r[j]);
        *(short8*)((unsigned short*)outp + (size_t)row * CH + base) = ov;
    } else {
        float* o = (float*)outp + (size_t)row * CH + base;
        *(float4*)o = make_float4(r[0], r[1], r[2], r[3]);
        *(float4*)(o + 4) = make_float4(r[4], r[5], r[6], r[7]);
    }
}

// ---------------- RoPE table (fp64, replicating np's correctly-rounded fp32) ----
__global__ void rope_tab_k(float2* __restrict__ tab) {
    int i = blockIdx.x * 256 + threadIdx.x;   // 2048*64
    int p = i >> 6, j = i & 63;
    double inv = pow(10000.0, -(double)j / 64.0);
    float invf = (float)inv;                  // = correctly-rounded fp32 inv_freq
    float angf = (float)p * invf;             // fp32 multiply, as np does
    double da = (double)angf;
    tab[i] = make_float2((float)cos(da), (float)sin(da));
}

// ---------------- RoPE (in-place on fp32 q,k in qkv buffer) ----------------
__global__ __launch_bounds__(256) void rope_k(float* __restrict__ qkv,
                                              const int* __restrict__ pos,
                                              const float2* __restrict__ tab) {
    int i = blockIdx.x * 256 + threadIdx.x;  // CT*16*64
    if (i >= CT * CNH * 64) return;
    int t = i >> 10, hj = i & 1023, hh = hj >> 6, j = hj & 63;
    float2 cs = tab[(size_t)pos[t] * 64 + j];
    float* q = qkv + (size_t)t * CQKV + hh * CHD;
    float* k = q + CH;
    float x1 = q[j], x2 = q[j + 64];
    q[j]      = x1 * cs.x - x2 * cs.y;
    q[j + 64] = x2 * cs.x + x1 * cs.y;
    x1 = k[j]; x2 = k[j + 64];
    k[j]      = x1 * cs.x - x2 * cs.y;
    k[j + 64] = x2 * cs.x + x1 * cs.y;
}

// ---------------- precise split-bf16 GEMM: A f32 [MxK] x B f32 [KxN] ------------
// MODE 0: QKV — B from (q_w,k_w,v_w) by nt>>4, C f32
// MODE 1: C f32 = A@B + resid
template<int MODE>
__global__ __launch_bounds__(256) void pgemm_k(
    const float* __restrict__ A, int lda,
    const float* __restrict__ B0, const float* __restrict__ B1, const float* __restrict__ B2,
    int ldb, int K, float* __restrict__ C, int ldc, const float* __restrict__ resid) {
    __shared__ unsigned short Ah[128][40], Al[128][40];
    __shared__ unsigned short Bh[32][136], Bl[32][136];
    const int nt = blockIdx.x, mt = blockIdx.y, tid = threadIdx.x;
    const int m0 = mt * 128;
    const float* a_src = A + (size_t)(m0 + (tid >> 1)) * lda + (tid & 1) * 16;
    const float* src = B0; int col = nt * 128;
    if (MODE == 0) { int w = nt >> 4; src = (w == 0) ? B0 : ((w == 1) ? B1 : B2); col = (nt & 15) * 128; }
    const int kk = tid >> 3, slot = tid & 7;
    const float* bp = src + (size_t)kk * ldb + col + slot * 16;
    const int lane = tid & 63, lr = lane & 15, lg = lane >> 4;
    const int wr = (tid >> 7) & 1, wc = (tid >> 6) & 1;

    float4v acc[4][4];
    #pragma unroll
    for (int m = 0; m < 4; m++)
        #pragma unroll
        for (int n = 0; n < 4; n++) acc[m][n] = (float4v){0.f, 0.f, 0.f, 0.f};

    unsigned short* ahw = &Ah[tid >> 1][(tid & 1) * 16];
    unsigned short* alw = &Al[tid >> 1][(tid & 1) * 16];
    unsigned short* bhw = &Bh[kk][slot * 16];
    unsigned short* blw = &Bl[kk][slot * 16];

    for (int k0 = 0; k0 < K; k0 += 32) {
        short8 ah0, al0, ah1, al1, bh0, bl0, bh1, bl1;
        split8(a_src + k0, ah0, al0);
        split8(a_src + k0 + 8, ah1, al1);
        split8(bp, bh0, bl0);
        split8(bp + 8, bh1, bl1);
        bp += (size_t)32 * ldb;
        __syncthreads();
        *(short8*)ahw = ah0; *(short8*)(ahw + 8) = ah1;
        *(short8*)alw = al0; *(short8*)(alw + 8) = al1;
        *(short8*)bhw = bh0; *(short8*)(bhw + 8) = bh1;
        *(short8*)blw = bl0; *(short8*)(blw + 8) = bl1;
        __syncthreads();
        short8 fah[4], fal[4];
        #pragma unroll
        for (int m = 0; m < 4; m++) {
            fah[m] = *(const short8*)(&Ah[wr * 64 + m * 16 + lr][lg * 8]);
            fal[m] = *(const short8*)(&Al[wr * 64 + m * 16 + lr][lg * 8]);
        }
        #pragma unroll
        for (int n = 0; n < 4; n++) {
            short8 fbh, fbl;
            unsigned short* ph = (unsigned short*)&fbh;
            unsigned short* pl = (unsigned short*)&fbl;
            const int bc = wc * 64 + n * 16 + lr;
            #pragma unroll
            for (int j = 0; j < 8; j++) { ph[j] = Bh[lg * 8 + j][bc]; pl[j] = Bl[lg * 8 + j][bc]; }
            #pragma unroll
            for (int m = 0; m < 4; m++) {
                acc[m][n] = __builtin_amdgcn_mfma_f32_16x16x32_bf16(fal[m], fbl, acc[m][n], 0, 0, 0);
                acc[m][n] = __builtin_amdgcn_mfma_f32_16x16x32_bf16(fal[m], fbh, acc[m][n], 0, 0, 0);
                acc[m][n] = __builtin_amdgcn_mfma_f32_16x16x32_bf16(fah[m], fbl, acc[m][n], 0, 0, 0);
                acc[m][n] = __builtin_amdgcn_mfma_f32_16x16x32_bf16(fah[m], fbh, acc[m][n], 0, 0, 0);
            }
        }
    }
    #pragma unroll
    for (int m = 0; m < 4; m++) {
        const int rb = wr * 64 + m * 16 + lg * 4;
        #pragma unroll
        for (int n = 0; n < 4; n++) {
            const int ccol = nt * 128 + wc * 64 + n * 16 + lr;
            #pragma unroll
            for (int r = 0; r < 4; r++) {
                const size_t idx = (size_t)(m0 + rb + r) * ldc + ccol;
                C[idx] = (MODE == 1) ? (acc[m][n][r] + resid[idx]) : acc[m][n][r];
            }
        }
    }
}

// ---------------- fast bf16 GEMM for MoE ----------
// MODE 2: MoE up: A gathered by token list, B interleaved (w1,w3), SwiGLU -> bf16 H
// MODE 3: MoE down: A = Hbuf rows, epilogue gate*val atomicAdd into out
template<int MODE>
__global__ __launch_bounds__(256) void gemm_k(
    const unsigned short* __restrict__ A, int lda,
    const float* __restrict__ B0, const float* __restrict__ B1,
    int ldb, int K, void* __restrict__ Cp, int ldc,
    const int* __restrict__ cnt, const int* __restrict__ tokl,
    const float* __restrict__ gatel, const int* __restrict__ pb) {
    __shared__ unsigned short As[128][40];
    __shared__ unsigned short Bs[32][136];
    const int nt = blockIdx.x, mt = blockIdx.y;
    const int m0 = mt * 128;
    const int e = blockIdx.z;
    const int c = cnt[e];
    if (m0 >= c) return;
    const int valid = (c - m0 < 128) ? (c - m0) : 128;
    const int tid = threadIdx.x;

    const unsigned short* a_src;
    {
        const int row = tid >> 1;
        size_t gr;
        if (MODE == 2) {
            int idx = m0 + (row < valid ? row : valid - 1);
            gr = (size_t)tokl[e * 4096 + idx];
        } else {
            gr = (size_t)(pb[e] + m0 + row);
        }
        a_src = A + gr * (size_t)lda + (tid & 1) * 16;
    }
    const int kk = tid >> 3, slot = tid & 7;
    const float* bp0 = nullptr; const float* bp1 = nullptr;
    if (MODE == 2) {
        size_t eoff = (size_t)e * (size_t)K * ldb;
        int ch = nt * 64 + slot * 8;
        bp0 = B0 + eoff + (size_t)kk * ldb + ch;
        bp1 = B1 + eoff + (size_t)kk * ldb + ch;
    } else {
        bp0 = B0 + (size_t)e * (size_t)K * ldb + (size_t)kk * ldb + nt * 128 + slot * 16;
    }
    const int lane = tid & 63, lr = lane & 15, lg = lane >> 4;
    const int wr = (tid >> 7) & 1, wc = (tid >> 6) & 1;

    float4v acc[4][4];
    #pragma unroll
    for (int m = 0; m < 4; m++)
        #pragma unroll
        for (int n = 0; n < 4; n++) acc[m][n] = (float4v){0.f, 0.f, 0.f, 0.f};

    unsigned short* awp = &As[tid >> 1][(tid & 1) * 16];
    unsigned short* bwp = &Bs[kk][slot * 16];

    for (int k0 = 0; k0 < K; k0 += 32) {
        short8 av0 = *(const short8*)(a_src + k0);
        short8 av1 = *(const short8*)(a_src + k0 + 8);
        short8 bl, bh;
        {
            unsigned short* tl = (unsigned short*)&bl;
            unsigned short* th = (unsigned short*)&bh;
            if (MODE == 2) {
                float4 x0 = *(const float4*)(bp0);
                float4 x1 = *(const float4*)(bp0 + 4);
                float4 y0 = *(const float4*)(bp1);
                float4 y1 = *(const float4*)(bp1 + 4);
                bp0 += (size_t)32 * ldb; bp1 += (size_t)32 * ldb;
                tl[0] = f2bf(x0.x); tl[1] = f2bf(y0.x); tl[2] = f2bf(x0.y); tl[3] = f2bf(y0.y);
                tl[4] = f2bf(x0.z); tl[5] = f2bf(y0.z); tl[6] = f2bf(x0.w); tl[7] = f2bf(y0.w);
                th[0] = f2bf(x1.x); th[1] = f2bf(y1.x); th[2] = f2bf(x1.y); th[3] = f2bf(y1.y);
                th[4] = f2bf(x1.z); th[5] = f2bf(y1.z); th[6] = f2bf(x1.w); th[7] = f2bf(y1.w);
            } else {
                float4 x0 = *(const float4*)(bp0);
                float4 x1 = *(const float4*)(bp0 + 4);
                float4 x2 = *(const float4*)(bp0 + 8);
                float4 x3 = *(const float4*)(bp0 + 12);
                bp0 += (size_t)32 * ldb;
                tl[0] = f2bf(x0.x); tl[1] = f2bf(x0.y); tl[2] = f2bf(x0.z); tl[3] = f2bf(x0.w);
                tl[4] = f2bf(x1.x); tl[5] = f2bf(x1.y); tl[6] = f2bf(x1.z); tl[7] = f2bf(x1.w);
                th[0] = f2bf(x2.x); th[1] = f2bf(x2.y); th[2] = f2bf(x2.z); th[3] = f2bf(x2.w);
                th[4] = f2bf(x3.x); th[5] = f2bf(x3.y); th[6] = f2bf(x3.z); th[7] = f2bf(x3.w);
            }
        }
        __syncthreads();
        *(short8*)awp = av0; *(short8*)(awp + 8) = av1;
        *(short8*)bwp = bl;  *(short8*)(bwp + 8) = bh;
        __syncthreads();
        short8 af[4];
        #pragma unroll
        for (int m = 0; m < 4; m++) af[m] = *(const short8*)(&As[wr * 64 + m * 16 + lr][lg * 8]);
        #pragma unroll
        for (int n = 0; n < 4; n++) {
            short8 bf;
            unsigned short* bfp = (unsigned short*)&bf;
            const int bc = wc * 64 + n * 16 + lr;
            #pragma unroll
            for (int j = 0; j < 8; j++) bfp[j] = Bs[lg * 8 + j][bc];
            #pragma unroll
            for (int m = 0; m < 4; m++)
                acc[m][n] = __builtin_amdgcn_mfma_f32_16x16x32_bf16(af[m], bf, acc[m][n], 0, 0, 0);
        }
    }

    #pragma unroll
    for (int m = 0; m < 4; m++) {
        const int rb = wr * 64 + m * 16 + lg * 4;
        #pragma unroll
        for (int n = 0; n < 4; n++) {
            const int col = nt * 128 + wc * 64 + n * 16 + lr;
            #pragma unroll
            for (int r = 0; r < 4; r++) {
                const int row = rb + r;
                const float v = acc[m][n][r];
                if (MODE == 2) {
                    const float other = __shfl_xor(v, 1);
                    if (!(lr & 1) && row < valid) {
                        const float g1 = v, g3 = other;
                        const float hsw = (g1 / (1.f + __expf(-g1))) * g3;
                        ((unsigned short*)Cp)[(size_t)(pb[e] + m0 + row) * ldc + (col >> 1)] = f2bf(hsw);
                    }
                } else {
                    if (row < valid) {
                        const int t = tokl[e * 4096 + m0 + row];
                        const float g = gatel[e * 4096 + m0 + row];
                        atomicAdd(((float*)Cp) + (size_t)t * ldc + col, v * g);
                    }
                }
            }
        }
    }
}

// ---------------- flash attention, split-bf16 precise, fp32 in/out ----------
__global__ __launch_bounds__(256) void attn_k(const float* __restrict__ qkv,
                                              float* __restrict__ ctx) {
    __shared__ unsigned short Ksh[32][136], Ksl[32][136];
    __shared__ unsigned short Vth[128][40], Vtl[128][40];
    const int qb = blockIdx.x;
    const int h  = blockIdx.y;
    const int b  = blockIdx.z;
    const int tid = threadIdx.x;
    const int wave = tid >> 6, lane = tid & 63, lr = lane & 15, lg = lane >> 4;
    const size_t tb = (size_t)b * CS;
    const int q0 = qb * 64 + wave * 16;

    short8 qh[4], ql[4];
    {
        const float* qrow = qkv + (tb + q0 + lr) * CQKV + h * CHD;
        #pragma unroll
        for (int c = 0; c < 4; c++) split8(qrow + c * 32 + lg * 8, qh[c], ql[c]);
    }
    float4v o[8];
    #pragma unroll
    for (int d = 0; d < 8; d++) o[d] = (float4v){0.f, 0.f, 0.f, 0.f};
    float m = -1e30f, l = 0.f;
    const float scl = 0.08838834764831845f;  // 1/sqrt(128)
    const int ntiles = (qb * 64 + 64 + 31) >> 5;
    const int kk = tid >> 3, slot = tid & 7;

    for (int kt = 0; kt < ntiles; ++kt) {
        const int kv0 = kt * 32;
        __syncthreads();
        {
            const float* krow = qkv + (tb + kv0 + kk) * CQKV + CH + h * CHD + slot * 16;
            const float* vrow = krow + CH;
            short8 kh0, kl0, kh1, kl1;
            split8(krow, kh0, kl0);
            split8(krow + 8, kh1, kl1);
            *(short8*)(&Ksh[kk][slot * 16])     = kh0;
            *(short8*)(&Ksh[kk][slot * 16 + 8]) = kh1;
            *(short8*)(&Ksl[kk][slot * 16])     = kl0;
            *(short8*)(&Ksl[kk][slot * 16 + 8]) = kl1;
            float vv[16];
            *(float4*)(vv)      = *(const float4*)(vrow);
            *(float4*)(vv + 4)  = *(const float4*)(vrow + 4);
            *(float4*)(vv + 8)  = *(const float4*)(vrow + 8);
            *(float4*)(vv + 12) = *(const float4*)(vrow + 12);
            #pragma unroll
            for (int j = 0; j < 16; j++) {
                unsigned short hh = f2bf(vv[j]);
                Vth[slot * 16 + j][kk] = hh;
                Vtl[slot * 16 + j][kk] = f2bf(vv[j] - bf2f(hh));
            }
        }
        __syncthreads();

        float4v st0 = (float4v){0.f,0.f,0.f,0.f}, st1 = st0;
        #pragma unroll
        for (int c = 0; c < 4; c++) {
            short8 kah = *(const short8*)(&Ksh[lr][c * 32 + lg * 8]);
            short8 kal = *(const short8*)(&Ksl[lr][c * 32 + lg * 8]);
            short8 kbh = *(const short8*)(&Ksh[16 + lr][c * 32 + lg * 8]);
            short8 kbl = *(const short8*)(&Ksl[16 + lr][c * 32 + lg * 8]);
            st0 = __builtin_amdgcn_mfma_f32_16x16x32_bf16(kal, ql[c], st0, 0, 0, 0);
            st0 = __builtin_amdgcn_mfma_f32_16x16x32_bf16(kal, qh[c], st0, 0, 0, 0);
            st0 = __builtin_amdgcn_mfma_f32_16x16x32_bf16(kah, ql[c], st0, 0, 0, 0);
            st0 = __builtin_amdgcn_mfma_f32_16x16x32_bf16(kah, qh[c], st0, 0, 0, 0);
            st1 = __builtin_amdgcn_mfma_f32_16x16x32_bf16(kbl, ql[c], st1, 0, 0, 0);
            st1 = __builtin_amdgcn_mfma_f32_16x16x32_bf16(kbl, qh[c], st1, 0, 0, 0);
            st1 = __builtin_amdgcn_mfma_f32_16x16x32_bf16(kbh, ql[c], st1, 0, 0, 0);
            st1 = __builtin_amdgcn_mfma_f32_16x16x32_bf16(kbh, qh[c], st1, 0, 0, 0);
        }
        float pv[8]; float pmax = -1e30f;
        const int qg = q0 + lr;
        #pragma unroll
        for (int f = 0; f < 2; f++) {
            #pragma unroll
            for (int r = 0; r < 4; r++) {
                const int kg = kv0 + f * 16 + lg * 4 + r;
                const float s = (kg <= qg) ? ((f ? st1[r] : st0[r]) * scl) : -1e30f;
                pv[f * 4 + r] = s;
                pmax = fmaxf(pmax, s);
            }
        }
        pmax = fmaxf(pmax, __shfl_xor(pmax, 16));
        pmax = fmaxf(pmax, __shfl_xor(pmax, 32));
        const float mnew = fmaxf(m, pmax);
        const float alpha = __expf(m - mnew);
        float sum = 0.f;
        #pragma unroll
        for (int i = 0; i < 8; i++) { const float p = __expf(pv[i] - mnew); pv[i] = p; sum += p; }
        sum += __shfl_xor(sum, 16);
        sum += __shfl_xor(sum, 32);
        l = l * alpha + sum;
        m = mnew;
        #pragma unroll
        for (int d = 0; d < 8; d++) o[d] *= alpha;
        // rebuild P^T hi/lo fragments via shuffles (same q stays in lane&15)
        short8 pfh, pfl;
        unsigned short* pfhp = (unsigned short*)&pfh;
        unsigned short* pflp = (unsigned short*)&pfl;
        #pragma unroll
        for (int j = 0; j < 8; j++) {
            const int srcl = (((lg & 1) * 2 + (j >> 2)) << 4) | lr;
            const float a0 = __shfl(pv[j & 3], srcl);
            const float a1 = __shfl(pv[4 + (j & 3)], srcl);
            const float sel = (lg >= 2) ? a1 : a0;
            unsigned short hh = f2bf(sel);
            pfhp[j] = hh;
            pflp[j] = f2bf(sel - bf2f(hh));
        }
        #pragma unroll
        for (int dt = 0; dt < 8; dt++) {
            short8 vh = *(const short8*)(&Vth[dt * 16 + lr][lg * 8]);
            short8 vl = *(const short8*)(&Vtl[dt * 16 + lr][lg * 8]);
            o[dt] = __builtin_amdgcn_mfma_f32_16x16x32_bf16(vl, pfl, o[dt], 0, 0, 0);
            o[dt] = __builtin_amdgcn_mfma_f32_16x16x32_bf16(vl, pfh, o[dt], 0, 0, 0);
            o[dt] = __builtin_amdgcn_mfma_f32_16x16x32_bf16(vh, pfl, o[dt], 0, 0, 0);
            o[dt] = __builtin_amdgcn_mfma_f32_16x16x32_bf16(vh, pfh, o[dt], 0, 0, 0);
        }
    }
    const float inv = 1.f / l;
    float* crow = ctx + (tb + q0 + lr) * CH + h * CHD + lg * 4;
    #pragma unroll
    for (int dt = 0; dt < 8; dt++) {
        *(float4*)(crow + dt * 16) = make_float4(o[dt][0] * inv, o[dt][1] * inv,
                                                 o[dt][2] * inv, o[dt][3] * inv);
    }
}

// ---------------- router: fp64 logits + top2 ----------------
__global__ __launch_bounds__(64) void router_k(const float* __restrict__ x,
                                               const float* __restrict__ wn,
                                               const float* __restrict__ rw,
                                               int* __restrict__ cnt, int* __restrict__ tok,
                                               float* __restrict__ gate) {
    const int t = blockIdx.x;
    const int lane = threadIdx.x;
    const float* xr = x + (size_t)t * CH;
    double ss = 0.0;
    double acc[8] = {0,0,0,0,0,0,0,0};
    for (int i = lane * 4; i < CH; i += 256) {
        float4 v = *(const float4*)(xr + i);
        float4 wv = *(const float4*)(wn + i);
        ss += (double)v.x*v.x + (double)v.y*v.y + (double)v.z*v.z + (double)v.w*v.w;
        float xs[4] = {v.x, v.y, v.z, v.w};
        float ws4[4] = {wv.x, wv.y, wv.z, wv.w};
        #pragma unroll
        for (int dd = 0; dd < 4; dd++) {
            const double xn = (double)xs[dd] * (double)ws4[dd];
            const float* rr = rw + (size_t)(i + dd) * CE;
            #pragma unroll
            for (int e2 = 0; e2 < 8; e2++) acc[e2] += xn * (double)rr[e2];
        }
    }
    #pragma unroll
    for (int o = 1; o < 64; o <<= 1) ss += __shfl_xor(ss, o);
    #pragma unroll
    for (int e2 = 0; e2 < 8; e2++) {
        #pragma unroll
        for (int o = 1; o < 64; o <<= 1) acc[e2] += __shfl_xor(acc[e2], o);
    }
    if (lane == 0) {
        const double scale = rsqrt(ss / (double)CH + 1e-5);
        int e0 = 0;
        #pragma unroll
        for (int e2 = 1; e2 < 8; e2++) if (acc[e2] > acc[e0]) e0 = e2;
        int e1 = (e0 == 0) ? 1 : 0;
        #pragma unroll
        for (int e2 = 0; e2 < 8; e2++) if (e2 != e0 && acc[e2] > acc[e1]) e1 = e2;
        const double dl = scale * (acc[e1] - acc[e0]);   // <= 0
        const double p1r = exp(dl);
        const float g0 = (float)(1.0 / (1.0 + p1r));
        const float g1 = (float)(p1r / (1.0 + p1r));
        int pos0 = atomicAdd(&cnt[e0], 1);
        tok[e0 * 4096 + pos0] = t; gate[e0 * 4096 + pos0] = g0;
        int pos1 = atomicAdd(&cnt[e1], 1);
        tok[e1 * 4096 + pos1] = t; gate[e1 * 4096 + pos1] = g1;
    }
}

__global__ void prefix_k(const int* __restrict__ cnt, int* __restrict__ pb) {
    if (threadIdx.x == 0 && blockIdx.x == 0) {
        int s = 0;
        for (int e = 0; e < CE; e++) { pb[e] = s; s += (cnt[e] + 127) & ~127; }
    }
}

// ---------------- launch ----------------
extern "C" void kernel_launch(void* const* d_in, const int* in_sizes, int n_in,
                              void* d_out, int out_size, void* d_ws, size_t ws_size,
                              hipStream_t stream) {
    (void)in_sizes; (void)n_in; (void)out_size; (void)ws_size;
    const float* hidden = (const float*)d_in[0];
    const int*   posids = (const int*)d_in[1];
    const float* rms1w  = (const float*)d_in[2];
    const float* rms2w  = (const float*)d_in[3];
    const float* qw     = (const float*)d_in[4];
    const float* kw     = (const float*)d_in[5];
    const float* vw     = (const float*)d_in[6];
    const float* ow     = (const float*)d_in[7];
    const float* rw     = (const float*)d_in[8];
    const float* w1     = (const float*)d_in[9];
    const float* w2     = (const float*)d_in[10];
    const float* w3     = (const float*)d_in[11];
    float* out = (float*)d_out;

    char* ws = (char*)d_ws;
    // region A [0, 33.5MB): h1 (fp32), later res2 (fp32)
    float* h1_res2 = (float*)ws;
    // region B [33.5MB, 134.2MB): qkv fp32; reused later for h2/Hbuf/tok/gate/cnt/pb
    float* qkvf = (float*)(ws + 33554432);
    unsigned short* h2   = (unsigned short*)(ws + 33554432);
    unsigned short* Hbuf = (unsigned short*)(ws + 33554432 + 16777216);
    int*   tok  = (int*)(ws + 33554432 + 16777216 + 37748736);
    float* gate = (float*)(ws + 33554432 + 16777216 + 37748736 + 131072);
    int*   cnt  = (int*)(ws + 33554432 + 16777216 + 37748736 + 262144);
    int*   pb   = cnt + 16;
    // region C [134.2MB, ...): ctx fp32 + rope table
    float*  ctx  = (float*)(ws + 134217728);
    float2* rtab = (float2*)(ws + 134217728 + 33554432);

    rope_tab_k<<<512, 256, 0, stream>>>(rtab);
    rmsnorm_k<0><<<CT, 256, 0, stream>>>(hidden, rms1w, h1_res2);
    pgemm_k<0><<<dim3(48, 32), 256, 0, stream>>>(h1_res2, CH, qw, kw, vw, CH, CH, qkvf, CQKV, nullptr);
    rope_k<<<16384, 256, 0, stream>>>(qkvf, posids, rtab);
    attn_k<<<dim3(32, CNH, CB), 256, 0, stream>>>(qkvf, ctx);
    pgemm_k<1><<<dim3(16, 32), 256, 0, stream>>>(ctx, CH, ow, nullptr, nullptr, CH, CH, h1_res2, CH, hidden);
    rmsnorm_k<1><<<CT, 256, 0, stream>>>(h1_res2, rms2w, h2);
    hipMemsetAsync(cnt, 0, 8 * sizeof(int), stream);
    router_k<<<CT, 64, 0, stream>>>(h1_res2, rms2w, rw, cnt, tok, gate);
    prefix_k<<<1, 64, 0, stream>>>(cnt, pb);
    hipMemcpyAsync(out, h1_res2, (size_t)CT * CH * 4, hipMemcpyDeviceToDevice, stream);
    gemm_k<2><<<dim3(32, 32, 8), 256, 0, stream>>>(h2, CH, w1, w3, CI, CH, Hbuf, CI,
                                                   cnt, tok, gate, pb);
    gemm_k<3><<<dim3(16, 32, 8), 256, 0, stream>>>(Hbuf, CI, w2, nullptr, CH, CI, out, CH,
                                                   cnt, tok, gate, pb);
}

// Round 4
// 1715.170 us; speedup vs baseline: 1.1690x; 1.1690x over previous
//
#include <hip/hip_runtime.h>
#include <hip/hip_bf16.h>

// ---------------- constants ----------------
constexpr int CB   = 2;     // batch
constexpr int CS   = 2048;  // seq
constexpr int CH   = 2048;  // hidden
constexpr int CNH  = 16;    // heads
constexpr int CHD  = 128;   // head dim
constexpr int CE   = 8;     // experts
constexpr int CI   = 2048;  // ffn inner
constexpr int CT   = CB * CS;      // 4096 tokens
constexpr int CQKV = 3 * CH;       // 6144

typedef __attribute__((ext_vector_type(8))) short short8;
typedef __attribute__((ext_vector_type(4))) float float4v;
typedef unsigned int uint32;

union S8U4 { short8 s; uint4 u; };

__device__ __forceinline__ float bf2f(unsigned short u) {
    union { unsigned int i; float f; } x; x.i = ((unsigned int)u) << 16; return x.f;
}
__device__ __forceinline__ unsigned short f2bf(float f) {
    union { float f; unsigned int i; } x; x.f = f;
    unsigned int r = x.i + 0x7fffu + ((x.i >> 16) & 1u);
    return (unsigned short)(r >> 16);
}
// pack hi16 of r0 (low short) and r1 (high short)
__device__ __forceinline__ uint32 packpair(uint32 r0, uint32 r1) {
    return __builtin_amdgcn_perm(r1, r0, 0x07060302u);
}
__device__ __forceinline__ uint32 rnebits(float f) {
    uint32 u = __float_as_uint(f);
    return u + 0x7fffu + ((u >> 16) & 1u);
}
// two floats -> packed hi-pair and lo-pair (hi RNE, residual exact, lo RNE)
__device__ __forceinline__ void split2(float f0, float f1, uint32& h, uint32& l) {
    uint32 r0 = rnebits(f0), r1 = rnebits(f1);
    h = packpair(r0, r1);
    float d0 = f0 - __uint_as_float(r0 & 0xffff0000u);
    float d1 = f1 - __uint_as_float(r1 & 0xffff0000u);
    l = packpair(rnebits(d0), rnebits(d1));
}
// 16 floats (regs) -> 16 hi shorts + 16 lo shorts at 16B-aligned LDS
__device__ __forceinline__ void split16_store(const float* fv, unsigned short* hdst,
                                              unsigned short* ldst) {
    uint32 h[8], l[8];
    #pragma unroll
    for (int p = 0; p < 8; p++) split2(fv[2 * p], fv[2 * p + 1], h[p], l[p]);
    ((uint4*)hdst)[0] = make_uint4(h[0], h[1], h[2], h[3]);
    ((uint4*)hdst)[1] = make_uint4(h[4], h[5], h[6], h[7]);
    ((uint4*)ldst)[0] = make_uint4(l[0], l[1], l[2], l[3]);
    ((uint4*)ldst)[1] = make_uint4(l[4], l[5], l[6], l[7]);
}
// 16 floats -> 16 RNE bf16 shorts
__device__ __forceinline__ void rne16_store(const float* fv, unsigned short* dst) {
    uint32 h[8];
    #pragma unroll
    for (int p = 0; p < 8; p++) h[p] = packpair(rnebits(fv[2 * p]), rnebits(fv[2 * p + 1]));
    ((uint4*)dst)[0] = make_uint4(h[0], h[1], h[2], h[3]);
    ((uint4*)dst)[1] = make_uint4(h[4], h[5], h[6], h[7]);
}
// 8 consecutive floats -> hi/lo short8 (regs)
__device__ __forceinline__ void split8v(const float* s, short8& hi, short8& lo) {
    float4 a = *(const float4*)s, b = *(const float4*)(s + 4);
    float v[8] = {a.x, a.y, a.z, a.w, b.x, b.y, b.z, b.w};
    S8U4 H, L;
    uint32 h[4], l[4];
    #pragma unroll
    for (int p = 0; p < 4; p++) split2(v[2 * p], v[2 * p + 1], h[p], l[p]);
    H.u = make_uint4(h[0], h[1], h[2], h[3]);
    L.u = make_uint4(l[0], l[1], l[2], l[3]);
    hi = H.s; lo = L.s;
}

// ---------------- RMSNorm: fp32 in -> fp32 or bf16 out ----------------
template<int BF16OUT>
__global__ __launch_bounds__(256) void rmsnorm_k(const float* __restrict__ x,
                                                 const float* __restrict__ w,
                                                 void* __restrict__ outp) {
    const int row = blockIdx.x;
    const float* xr = x + (size_t)row * CH;
    const int base = threadIdx.x * 8;
    float4 v0 = *(const float4*)(xr + base);
    float4 v1 = *(const float4*)(xr + base + 4);
    float ss = v0.x*v0.x + v0.y*v0.y + v0.z*v0.z + v0.w*v0.w
             + v1.x*v1.x + v1.y*v1.y + v1.z*v1.z + v1.w*v1.w;
    #pragma unroll
    for (int o = 1; o < 64; o <<= 1) ss += __shfl_xor(ss, o);
    __shared__ float ps[4];
    if ((threadIdx.x & 63) == 0) ps[threadIdx.x >> 6] = ss;
    __syncthreads();
    const float scale = rsqrtf((ps[0] + ps[1] + ps[2] + ps[3]) / (float)CH + 1e-5f);
    float4 w0 = *(const float4*)(w + base);
    float4 w1 = *(const float4*)(w + base + 4);
    float r[8] = {v0.x * scale * w0.x, v0.y * scale * w0.y, v0.z * scale * w0.z, v0.w * scale * w0.w,
                  v1.x * scale * w1.x, v1.y * scale * w1.y, v1.z * scale * w1.z, v1.w * scale * w1.w};
    if (BF16OUT) {
        rne16_store(r, (unsigned short*)outp + (size_t)row * CH + base);
    } else {
        float* o = (float*)outp + (size_t)row * CH + base;
        *(float4*)o = make_float4(r[0], r[1], r[2], r[3]);
        *(float4*)(o + 4) = make_float4(r[4], r[5], r[6], r[7]);
    }
}

// ---------------- RoPE table (fp64, replicating np's correctly-rounded fp32) ----
__global__ void rope_tab_k(float2* __restrict__ tab) {
    int i = blockIdx.x * 256 + threadIdx.x;   // 2048*64
    int p = i >> 6, j = i & 63;
    double inv = pow(10000.0, -(double)j / 64.0);
    float invf = (float)inv;
    float angf = (float)p * invf;
    double da = (double)angf;
    tab[i] = make_float2((float)cos(da), (float)sin(da));
}

// ---------------- RoPE (in-place on fp32 q,k in qkv buffer) ----------------
__global__ __launch_bounds__(256) void rope_k(float* __restrict__ qkv,
                                              const int* __restrict__ pos,
                                              const float2* __restrict__ tab) {
    int i = blockIdx.x * 256 + threadIdx.x;  // CT*16*64
    if (i >= CT * CNH * 64) return;
    int t = i >> 10, hj = i & 1023, hh = hj >> 6, j = hj & 63;
    float2 cs = tab[(size_t)pos[t] * 64 + j];
    float* q = qkv + (size_t)t * CQKV + hh * CHD;
    float* k = q + CH;
    float x1 = q[j], x2 = q[j + 64];
    q[j]      = x1 * cs.x - x2 * cs.y;
    q[j + 64] = x2 * cs.x + x1 * cs.y;
    x1 = k[j]; x2 = k[j + 64];
    k[j]      = x1 * cs.x - x2 * cs.y;
    k[j + 64] = x2 * cs.x + x1 * cs.y;
}

// ---------------- precise split-bf16 GEMM: A f32 [MxK] x B f32 [KxN] ------------
// B staged TRANSPOSED [col][k] so both fragments read as ds_read_b128.
// MODE 0: QKV — B from (q_w,k_w,v_w) by nt>>4, C f32
// MODE 1: C f32 = A@B + resid  (dual-store to C2 as well)
template<int MODE>
__global__ __launch_bounds__(256) void pgemm_k(
    const float* __restrict__ A, int lda,
    const float* __restrict__ B0, const float* __restrict__ B1, const float* __restrict__ B2,
    int ldb, int K, float* __restrict__ C, int ldc, const float* __restrict__ resid,
    float* __restrict__ C2) {
    __shared__ unsigned short Ah[128][40], Al[128][40];
    __shared__ unsigned short Bh[128][40], Bl[128][40];
    const int nt = blockIdx.x, mt = blockIdx.y, tid = threadIdx.x;
    const int m0 = mt * 128;
    const int arow = tid >> 1, acol = tid & 1;
    const float* a_src = A + (size_t)(m0 + arow) * lda + acol * 16;
    const float* src = B0; int col0 = nt * 128;
    if (MODE == 0) { int w = nt >> 4; src = (w == 0) ? B0 : ((w == 1) ? B1 : B2); col0 = (nt & 15) * 128; }
    const int bc_ = tid & 127, bhalf = tid >> 7;
    const float* bcol = src + col0 + bc_;   // column strip, row stride = ldb
    const int lane = tid & 63, lr = lane & 15, lg = lane >> 4;
    const int wr = (tid >> 7) & 1, wc = (tid >> 6) & 1;

    float4v acc[4][4];
    #pragma unroll
    for (int m = 0; m < 4; m++)
        #pragma unroll
        for (int n = 0; n < 4; n++) acc[m][n] = (float4v){0.f, 0.f, 0.f, 0.f};

    for (int k0 = 0; k0 < K; k0 += 32) {
        float av[16];
        {
            float4 t0 = *(const float4*)(a_src + k0);
            float4 t1 = *(const float4*)(a_src + k0 + 4);
            float4 t2 = *(const float4*)(a_src + k0 + 8);
            float4 t3 = *(const float4*)(a_src + k0 + 12);
            av[0]=t0.x; av[1]=t0.y; av[2]=t0.z; av[3]=t0.w;
            av[4]=t1.x; av[5]=t1.y; av[6]=t1.z; av[7]=t1.w;
            av[8]=t2.x; av[9]=t2.y; av[10]=t2.z; av[11]=t2.w;
            av[12]=t3.x; av[13]=t3.y; av[14]=t3.z; av[15]=t3.w;
        }
        float bv[16];
        {
            const float* bp = bcol + (size_t)(k0 + bhalf * 16) * ldb;
            #pragma unroll
            for (int j = 0; j < 16; j++) bv[j] = bp[(size_t)j * ldb];
        }
        __syncthreads();
        split16_store(av, &Ah[arow][acol * 16], &Al[arow][acol * 16]);
        split16_store(bv, &Bh[bc_][bhalf * 16], &Bl[bc_][bhalf * 16]);
        __syncthreads();
        short8 fah[4], fal[4], fbh[4], fbl[4];
        #pragma unroll
        for (int m = 0; m < 4; m++) {
            fah[m] = *(const short8*)(&Ah[wr * 64 + m * 16 + lr][lg * 8]);
            fal[m] = *(const short8*)(&Al[wr * 64 + m * 16 + lr][lg * 8]);
        }
        #pragma unroll
        for (int n = 0; n < 4; n++) {
            fbh[n] = *(const short8*)(&Bh[wc * 64 + n * 16 + lr][lg * 8]);
            fbl[n] = *(const short8*)(&Bl[wc * 64 + n * 16 + lr][lg * 8]);
        }
        #pragma unroll
        for (int n = 0; n < 4; n++)
            #pragma unroll
            for (int m = 0; m < 4; m++) {
                acc[m][n] = __builtin_amdgcn_mfma_f32_16x16x32_bf16(fal[m], fbh[n], acc[m][n], 0, 0, 0);
                acc[m][n] = __builtin_amdgcn_mfma_f32_16x16x32_bf16(fah[m], fbl[n], acc[m][n], 0, 0, 0);
                acc[m][n] = __builtin_amdgcn_mfma_f32_16x16x32_bf16(fah[m], fbh[n], acc[m][n], 0, 0, 0);
            }
    }
    #pragma unroll
    for (int m = 0; m < 4; m++) {
        const int rb = wr * 64 + m * 16 + lg * 4;
        #pragma unroll
        for (int n = 0; n < 4; n++) {
            const int ccol = nt * 128 + wc * 64 + n * 16 + lr;
            #pragma unroll
            for (int r = 0; r < 4; r++) {
                const size_t idx = (size_t)(m0 + rb + r) * ldc + ccol;
                if (MODE == 1) {
                    const float v = acc[m][n][r] + resid[idx];
                    C[idx] = v;
                    C2[idx] = v;
                } else {
                    C[idx] = acc[m][n][r];
                }
            }
        }
    }
}

// ---------------- fast bf16 GEMM for MoE (B staged transposed) ----------
// MODE 2: up: A gathered by token list, B cols interleaved (w1,w3), SwiGLU -> bf16 H
// MODE 3: down: A = Hbuf rows, epilogue gate*val atomicAdd into out
template<int MODE>
__global__ __launch_bounds__(256) void gemm_k(
    const unsigned short* __restrict__ A, int lda,
    const float* __restrict__ B0, const float* __restrict__ B1,
    int ldb, int K, void* __restrict__ Cp, int ldc,
    const int* __restrict__ cnt, const int* __restrict__ tokl,
    const float* __restrict__ gatel, const int* __restrict__ pb) {
    __shared__ unsigned short As[128][40];
    __shared__ unsigned short Bt[128][40];
    const int nt = blockIdx.x, mt = blockIdx.y;
    const int m0 = mt * 128;
    const int e = blockIdx.z;
    const int c = cnt[e];
    if (m0 >= c) return;
    const int valid = (c - m0 < 128) ? (c - m0) : 128;
    const int tid = threadIdx.x;

    const unsigned short* a_src;
    {
        const int row = tid >> 1;
        size_t gr;
        if (MODE == 2) {
            int idx = m0 + (row < valid ? row : valid - 1);
            gr = (size_t)tokl[e * 4096 + idx];
        } else {
            gr = (size_t)(pb[e] + m0 + row);
        }
        a_src = A + gr * (size_t)lda + (tid & 1) * 16;
    }
    const int bc_ = tid & 127, bhalf = tid >> 7;
    const float* bcol;
    if (MODE == 2) {
        const float* mat = (bc_ & 1) ? B1 : B0;
        bcol = mat + (size_t)e * CH * CI + nt * 64 + (bc_ >> 1);
    } else {
        bcol = B0 + (size_t)e * (size_t)K * ldb + nt * 128 + bc_;
    }
    const int lane = tid & 63, lr = lane & 15, lg = lane >> 4;
    const int wr = (tid >> 7) & 1, wc = (tid >> 6) & 1;

    float4v acc[4][4];
    #pragma unroll
    for (int m = 0; m < 4; m++)
        #pragma unroll
        for (int n = 0; n < 4; n++) acc[m][n] = (float4v){0.f, 0.f, 0.f, 0.f};

    for (int k0 = 0; k0 < K; k0 += 32) {
        short8 av0 = *(const short8*)(a_src + k0);
        short8 av1 = *(const short8*)(a_src + k0 + 8);
        float bv[16];
        {
            const float* bp = bcol + (size_t)(k0 + bhalf * 16) * ldb;
            #pragma unroll
            for (int j = 0; j < 16; j++) bv[j] = bp[(size_t)j * ldb];
        }
        __syncthreads();
        *(short8*)(&As[tid >> 1][(tid & 1) * 16]) = av0;
        *(short8*)(&As[tid >> 1][(tid & 1) * 16 + 8]) = av1;
        rne16_store(bv, &Bt[bc_][bhalf * 16]);
        __syncthreads();
        short8 af[4], bf[4];
        #pragma unroll
        for (int m = 0; m < 4; m++) af[m] = *(const short8*)(&As[wr * 64 + m * 16 + lr][lg * 8]);
        #pragma unroll
        for (int n = 0; n < 4; n++) bf[n] = *(const short8*)(&Bt[wc * 64 + n * 16 + lr][lg * 8]);
        #pragma unroll
        for (int n = 0; n < 4; n++)
            #pragma unroll
            for (int m = 0; m < 4; m++)
                acc[m][n] = __builtin_amdgcn_mfma_f32_16x16x32_bf16(af[m], bf[n], acc[m][n], 0, 0, 0);
    }

    #pragma unroll
    for (int m = 0; m < 4; m++) {
        const int rb = wr * 64 + m * 16 + lg * 4;
        #pragma unroll
        for (int n = 0; n < 4; n++) {
            const int col = nt * 128 + wc * 64 + n * 16 + lr;
            #pragma unroll
            for (int r = 0; r < 4; r++) {
                const int row = rb + r;
                const float v = acc[m][n][r];
                if (MODE == 2) {
                    const float other = __shfl_xor(v, 1);
                    if (!(lr & 1) && row < valid) {
                        const float g1 = v, g3 = other;
                        const float hsw = (g1 / (1.f + __expf(-g1))) * g3;
                        ((unsigned short*)Cp)[(size_t)(pb[e] + m0 + row) * ldc + (col >> 1)] = f2bf(hsw);
                    }
                } else {
                    if (row < valid) {
                        const int t = tokl[e * 4096 + m0 + row];
                        const float g = gatel[e * 4096 + m0 + row];
                        atomicAdd(((float*)Cp) + (size_t)t * ldc + col, v * g);
                    }
                }
            }
        }
    }
}

// ---------------- flash attention, split-bf16 precise, fp32 in/out ----------
__global__ __launch_bounds__(256) void attn_k(const float* __restrict__ qkv,
                                              float* __restrict__ ctx) {
    __shared__ unsigned short Ksh[32][136], Ksl[32][136];
    __shared__ unsigned short Vth[128][40], Vtl[128][40];
    const int qb = blockIdx.x;
    const int h  = blockIdx.y;
    const int b  = blockIdx.z;
    const int tid = threadIdx.x;
    const int wave = tid >> 6, lane = tid & 63, lr = lane & 15, lg = lane >> 4;
    const size_t tb = (size_t)b * CS;
    const int q0 = qb * 64 + wave * 16;

    short8 qh[4], ql[4];
    {
        const float* qrow = qkv + (tb + q0 + lr) * CQKV + h * CHD;
        #pragma unroll
        for (int c = 0; c < 4; c++) split8v(qrow + c * 32 + lg * 8, qh[c], ql[c]);
    }
    float4v o[8];
    #pragma unroll
    for (int d = 0; d < 8; d++) o[d] = (float4v){0.f, 0.f, 0.f, 0.f};
    float m = -1e30f, l = 0.f;
    const float scl = 0.08838834764831845f;  // 1/sqrt(128)
    const int ntiles = (qb * 64 + 64 + 31) >> 5;
    const int kk = tid >> 3, slot = tid & 7;
    const int vd = tid & 127, vhalf = tid >> 7;

    for (int kt = 0; kt < ntiles; ++kt) {
        const int kv0 = kt * 32;
        __syncthreads();
        {
            const float* krow = qkv + (tb + kv0 + kk) * CQKV + CH + h * CHD + slot * 16;
            short8 kh0, kl0, kh1, kl1;
            split8v(krow, kh0, kl0);
            split8v(krow + 8, kh1, kl1);
            *(short8*)(&Ksh[kk][slot * 16])     = kh0;
            *(short8*)(&Ksh[kk][slot * 16 + 8]) = kh1;
            *(short8*)(&Ksl[kk][slot * 16])     = kl0;
            *(short8*)(&Ksl[kk][slot * 16 + 8]) = kl1;
            // V: column-strip load (lanes over d -> coalesced), transposed b128 writes
            const float* vbase = qkv + (tb + kv0 + vhalf * 16) * CQKV + 2 * CH + h * CHD + vd;
            float vv[16];
            #pragma unroll
            for (int j = 0; j < 16; j++) vv[j] = vbase[(size_t)j * CQKV];
            split16_store(vv, &Vth[vd][vhalf * 16], &Vtl[vd][vhalf * 16]);
        }
        __syncthreads();

        float4v st0 = (float4v){0.f,0.f,0.f,0.f}, st1 = st0;
        #pragma unroll
        for (int c = 0; c < 4; c++) {
            short8 kah = *(const short8*)(&Ksh[lr][c * 32 + lg * 8]);
            short8 kal = *(const short8*)(&Ksl[lr][c * 32 + lg * 8]);
            short8 kbh = *(const short8*)(&Ksh[16 + lr][c * 32 + lg * 8]);
            short8 kbl = *(const short8*)(&Ksl[16 + lr][c * 32 + lg * 8]);
            st0 = __builtin_amdgcn_mfma_f32_16x16x32_bf16(kal, qh[c], st0, 0, 0, 0);
            st0 = __builtin_amdgcn_mfma_f32_16x16x32_bf16(kah, ql[c], st0, 0, 0, 0);
            st0 = __builtin_amdgcn_mfma_f32_16x16x32_bf16(kah, qh[c], st0, 0, 0, 0);
            st1 = __builtin_amdgcn_mfma_f32_16x16x32_bf16(kbl, qh[c], st1, 0, 0, 0);
            st1 = __builtin_amdgcn_mfma_f32_16x16x32_bf16(kbh, ql[c], st1, 0, 0, 0);
            st1 = __builtin_amdgcn_mfma_f32_16x16x32_bf16(kbh, qh[c], st1, 0, 0, 0);
        }
        float pv[8]; float pmax = -1e30f;
        const int qg = q0 + lr;
        #pragma unroll
        for (int f = 0; f < 2; f++) {
            #pragma unroll
            for (int r = 0; r < 4; r++) {
                const int kg = kv0 + f * 16 + lg * 4 + r;
                const float s = (kg <= qg) ? ((f ? st1[r] : st0[r]) * scl) : -1e30f;
                pv[f * 4 + r] = s;
                pmax = fmaxf(pmax, s);
            }
        }
        pmax = fmaxf(pmax, __shfl_xor(pmax, 16));
        pmax = fmaxf(pmax, __shfl_xor(pmax, 32));
        const float mnew = fmaxf(m, pmax);
        const float alpha = __expf(m - mnew);
        float sum = 0.f;
        #pragma unroll
        for (int i = 0; i < 8; i++) { const float p = __expf(pv[i] - mnew); pv[i] = p; sum += p; }
        sum += __shfl_xor(sum, 16);
        sum += __shfl_xor(sum, 32);
        l = l * alpha + sum;
        m = mnew;
        #pragma unroll
        for (int d = 0; d < 8; d++) o[d] *= alpha;
        // rebuild P^T hi/lo fragments via shuffles (same q stays in lane&15)
        short8 pfh, pfl;
        unsigned short* pfhp = (unsigned short*)&pfh;
        unsigned short* pflp = (unsigned short*)&pfl;
        #pragma unroll
        for (int j = 0; j < 8; j++) {
            const int srcl = (((lg & 1) * 2 + (j >> 2)) << 4) | lr;
            const float a0 = __shfl(pv[j & 3], srcl);
            const float a1 = __shfl(pv[4 + (j & 3)], srcl);
            const float sel = (lg >= 2) ? a1 : a0;
            uint32 r = rnebits(sel);
            pfhp[j] = (unsigned short)(r >> 16);
            float d = sel - __uint_as_float(r & 0xffff0000u);
            pflp[j] = (unsigned short)(rnebits(d) >> 16);
        }
        #pragma unroll
        for (int dt = 0; dt < 8; dt++) {
            short8 vh = *(const short8*)(&Vth[dt * 16 + lr][lg * 8]);
            short8 vl = *(const short8*)(&Vtl[dt * 16 + lr][lg * 8]);
            o[dt] = __builtin_amdgcn_mfma_f32_16x16x32_bf16(vl, pfh, o[dt], 0, 0, 0);
            o[dt] = __builtin_amdgcn_mfma_f32_16x16x32_bf16(vh, pfl, o[dt], 0, 0, 0);
            o[dt] = __builtin_amdgcn_mfma_f32_16x16x32_bf16(vh, pfh, o[dt], 0, 0, 0);
        }
    }
    const float inv = 1.f / l;
    float* crow = ctx + (tb + q0 + lr) * CH + h * CHD + lg * 4;
    #pragma unroll
    for (int dt = 0; dt < 8; dt++) {
        *(float4*)(crow + dt * 16) = make_float4(o[dt][0] * inv, o[dt][1] * inv,
                                                 o[dt][2] * inv, o[dt][3] * inv);
    }
}

// ---------------- router: fp64 logits + top2 ----------------
__global__ __launch_bounds__(64) void router_k(const float* __restrict__ x,
                                               const float* __restrict__ wn,
                                               const float* __restrict__ rw,
                                               int* __restrict__ cnt, int* __restrict__ tok,
                                               float* __restrict__ gate) {
    const int t = blockIdx.x;
    const int lane = threadIdx.x;
    const float* xr = x + (size_t)t * CH;
    double ss = 0.0;
    double acc[8] = {0,0,0,0,0,0,0,0};
    for (int i = lane * 4; i < CH; i += 256) {
        float4 v = *(const float4*)(xr + i);
        float4 wv = *(const float4*)(wn + i);
        ss += (double)v.x*v.x + (double)v.y*v.y + (double)v.z*v.z + (double)v.w*v.w;
        float xs[4] = {v.x, v.y, v.z, v.w};
        float ws4[4] = {wv.x, wv.y, wv.z, wv.w};
        #pragma unroll
        for (int dd = 0; dd < 4; dd++) {
            const double xn = (double)xs[dd] * (double)ws4[dd];
            const float* rr = rw + (size_t)(i + dd) * CE;
            #pragma unroll
            for (int e2 = 0; e2 < 8; e2++) acc[e2] += xn * (double)rr[e2];
        }
    }
    #pragma unroll
    for (int o = 1; o < 64; o <<= 1) ss += __shfl_xor(ss, o);
    #pragma unroll
    for (int e2 = 0; e2 < 8; e2++) {
        #pragma unroll
        for (int o = 1; o < 64; o <<= 1) acc[e2] += __shfl_xor(acc[e2], o);
    }
    if (lane == 0) {
        const double scale = rsqrt(ss / (double)CH + 1e-5);
        int e0 = 0;
        #pragma unroll
        for (int e2 = 1; e2 < 8; e2++) if (acc[e2] > acc[e0]) e0 = e2;
        int e1 = (e0 == 0) ? 1 : 0;
        #pragma unroll
        for (int e2 = 0; e2 < 8; e2++) if (e2 != e0 && acc[e2] > acc[e1]) e1 = e2;
        const double dl = scale * (acc[e1] - acc[e0]);   // <= 0
        const double p1r = exp(dl);
        const float g0 = (float)(1.0 / (1.0 + p1r));
        const float g1 = (float)(p1r / (1.0 + p1r));
        int pos0 = atomicAdd(&cnt[e0], 1);
        tok[e0 * 4096 + pos0] = t; gate[e0 * 4096 + pos0] = g0;
        int pos1 = atomicAdd(&cnt[e1], 1);
        tok[e1 * 4096 + pos1] = t; gate[e1 * 4096 + pos1] = g1;
    }
}

__global__ void prefix_k(const int* __restrict__ cnt, int* __restrict__ pb) {
    if (threadIdx.x == 0 && blockIdx.x == 0) {
        int s = 0;
        for (int e = 0; e < CE; e++) { pb[e] = s; s += (cnt[e] + 127) & ~127; }
    }
}

// ---------------- launch ----------------
extern "C" void kernel_launch(void* const* d_in, const int* in_sizes, int n_in,
                              void* d_out, int out_size, void* d_ws, size_t ws_size,
                              hipStream_t stream) {
    (void)in_sizes; (void)n_in; (void)out_size; (void)ws_size;
    const float* hidden = (const float*)d_in[0];
    const int*   posids = (const int*)d_in[1];
    const float* rms1w  = (const float*)d_in[2];
    const float* rms2w  = (const float*)d_in[3];
    const float* qw     = (const float*)d_in[4];
    const float* kw     = (const float*)d_in[5];
    const float* vw     = (const float*)d_in[6];
    const float* ow     = (const float*)d_in[7];
    const float* rw     = (const float*)d_in[8];
    const float* w1     = (const float*)d_in[9];
    const float* w2     = (const float*)d_in[10];
    const float* w3     = (const float*)d_in[11];
    float* out = (float*)d_out;

    char* ws = (char*)d_ws;
    float* h1_res2 = (float*)ws;
    float* qkvf = (float*)(ws + 33554432);
    unsigned short* h2   = (unsigned short*)(ws + 33554432);
    unsigned short* Hbuf = (unsigned short*)(ws + 33554432 + 16777216);
    int*   tok  = (int*)(ws + 33554432 + 16777216 + 37748736);
    float* gate = (float*)(ws + 33554432 + 16777216 + 37748736 + 131072);
    int*   cnt  = (int*)(ws + 33554432 + 16777216 + 37748736 + 262144);
    int*   pb   = cnt + 16;
    float*  ctx  = (float*)(ws + 134217728);
    float2* rtab = (float2*)(ws + 134217728 + 33554432);

    rope_tab_k<<<512, 256, 0, stream>>>(rtab);
    rmsnorm_k<0><<<CT, 256, 0, stream>>>(hidden, rms1w, h1_res2);
    pgemm_k<0><<<dim3(48, 32), 256, 0, stream>>>(h1_res2, CH, qw, kw, vw, CH, CH, qkvf, CQKV,
                                                 nullptr, nullptr);
    rope_k<<<16384, 256, 0, stream>>>(qkvf, posids, rtab);
    attn_k<<<dim3(32, CNH, CB), 256, 0, stream>>>(qkvf, ctx);
    pgemm_k<1><<<dim3(16, 32), 256, 0, stream>>>(ctx, CH, ow, nullptr, nullptr, CH, CH, h1_res2, CH,
                                                 hidden, out);
    rmsnorm_k<1><<<CT, 256, 0, stream>>>(h1_res2, rms2w, h2);
    hipMemsetAsync(cnt, 0, 8 * sizeof(int), stream);
    router_k<<<CT, 64, 0, stream>>>(h1_res2, rms2w, rw, cnt, tok, gate);
    prefix_k<<<1, 64, 0, stream>>>(cnt, pb);
    gemm_k<2><<<dim3(32, 32, 8), 256, 0, stream>>>(h2, CH, w1, w3, CI, CH, Hbuf, CI,
                                                   cnt, tok, gate, pb);
    gemm_k<3><<<dim3(16, 32, 8), 256, 0, stream>>>(Hbuf, CI, w2, nullptr, CH, CI, out, CH,
                                                   cnt, tok, gate, pb);
}